// Round 8
// baseline (48.491 us; speedup 1.0000x reference)
//
#include <hip/hip_runtime.h>
#include <hip/hip_fp16.h>

// term = log(sigmoid(x) + 1e-8) ~= -log(1 + min(exp(-x), 1e8))
// 1e8 clamp implements the +1e-8 floor (-log(1+1e8) = -18.42). Band error
// x in [-20,-16]: <=0.69/term, ~0.3% population -> ~2e3 total << 9.6e4 thr.
// 4-way log pairing: prod (1+t_k) <= 1e32 < fp32 max. 10 trans / 8 terms.
// Numerics identical to R3/R7 (passed, absmax 0.0).
//
// R8 single variable vs R7: table gathers issued as inline-asm
// global_load_dwordx4 ... sc0 (L1-bypass read from L2) to dodge the
// fitted ~4 cyc/L1-miss MSHR wall. All 8 gathers + s_waitcnt vmcnt(0)
// live in ONE asm block so the compiler cannot schedule consumers into
// the load->wait gap (reg-only ops aren't ordered by "memory" clobbers).

typedef unsigned int u32x4 __attribute__((ext_vector_type(4)));
typedef int          i32x4 __attribute__((ext_vector_type(4)));

__device__ __forceinline__ float edge_term(u32x4 A, u32x4 B) {
    float t[8];
#pragma unroll
    for (int k = 0; k < 4; ++k) {
        __half2 a = __builtin_bit_cast(__half2, A[k]);
        __half2 b = __builtin_bit_cast(__half2, B[k]);
        __half2 xh = __hmul2(a, b);          // inf-safe: limits correct
        float2 xf = __half22float2(xh);
        t[2 * k]     = fminf(__expf(-xf.x), 1.0e8f);
        t[2 * k + 1] = fminf(__expf(-xf.y), 1.0e8f);
    }
    float p0 = 1.0f + t[0];
    p0 = __builtin_fmaf(p0, t[1], p0);
    p0 = __builtin_fmaf(p0, t[2], p0);
    p0 = __builtin_fmaf(p0, t[3], p0);
    float p1 = 1.0f + t[4];
    p1 = __builtin_fmaf(p1, t[5], p1);
    p1 = __builtin_fmaf(p1, t[6], p1);
    p1 = __builtin_fmaf(p1, t[7], p1);
    return __logf(p0) + __logf(p1);          // positive; negated at the end
}

// ---------------- K0: c[n][0..7] fp16 packed (16 B/node); last block zeroes out
__global__ void compute_c_h8(const float* __restrict__ mu,
                             const float* __restrict__ ls,
                             const float* __restrict__ eps,
                             __half2* __restrict__ c, int N,
                             float* __restrict__ out, int out_size) {
    if (blockIdx.x == gridDim.x - 1) {
        for (int i = threadIdx.x; i < out_size; i += blockDim.x) out[i] = 0.0f;
        return;
    }
    int n = blockIdx.x * blockDim.x + threadIdx.x;
    if (n >= N) return;
    float m  = mu[n];
    float sg = __expf(ls[n]);
    float v[8];
#pragma unroll
    for (int s = 0; s < 8; ++s) v[s] = m + sg * eps[(size_t)s * N + n];
    __half2* dst = c + (size_t)n * 4;
#pragma unroll
    for (int s = 0; s < 4; ++s) dst[s] = __floats2half2_rn(v[2 * s], v[2 * s + 1]);
}

// ---------------- edge kernel: R7 structure, sc0 (L1-bypass) table gathers
__global__ void __launch_bounds__(256, 8)
edge_loglik_s8(const i32x4* __restrict__ ep, const u32x4* __restrict__ c,
               float* __restrict__ out, long long E, float neg_inv_s) {
    long long tid    = (long long)blockIdx.x * blockDim.x + threadIdx.x;
    long long stride = (long long)gridDim.x * blockDim.x;
    float acc = 0.0f;
    long long P = E >> 1;                    // edge-pairs (4 ints each)

    for (long long q = tid; q < P; q += 2 * stride) {
        long long q1 = q + stride;
        bool has1 = q1 < P;
        i32x4 e0 = __builtin_nontemporal_load(ep + q);        // stream: no-alloc
        i32x4 e1 = has1 ? __builtin_nontemporal_load(ep + q1) : e0;

        const u32x4* p0 = c + e0.x;
        const u32x4* p1 = c + e0.y;
        const u32x4* p2 = c + e0.z;
        const u32x4* p3 = c + e0.w;
        const u32x4* p4 = c + e1.x;
        const u32x4* p5 = c + e1.y;
        const u32x4* p6 = c + e1.z;
        const u32x4* p7 = c + e1.w;

        u32x4 a0, b0, d0, f0, a1, b1, d1, f1;
        // 8 L1-bypass gathers in flight, then wait -- all in one asm block
        asm volatile(
            "global_load_dwordx4 %0, %8,  off sc0\n\t"
            "global_load_dwordx4 %1, %9,  off sc0\n\t"
            "global_load_dwordx4 %2, %10, off sc0\n\t"
            "global_load_dwordx4 %3, %11, off sc0\n\t"
            "global_load_dwordx4 %4, %12, off sc0\n\t"
            "global_load_dwordx4 %5, %13, off sc0\n\t"
            "global_load_dwordx4 %6, %14, off sc0\n\t"
            "global_load_dwordx4 %7, %15, off sc0\n\t"
            "s_waitcnt vmcnt(0)"
            : "=&v"(a0), "=&v"(b0), "=&v"(d0), "=&v"(f0),
              "=&v"(a1), "=&v"(b1), "=&v"(d1), "=&v"(f1)
            : "v"(p0), "v"(p1), "v"(p2), "v"(p3),
              "v"(p4), "v"(p5), "v"(p6), "v"(p7)
            : "memory");

        float s = edge_term(a0, b0) + edge_term(d0, f0);
        if (has1) s += edge_term(a1, b1) + edge_term(d1, f1);
        acc += s;
    }
    if ((E & 1) && tid == 0) {
        const int2* el = (const int2*)ep;
        int2 ij = el[E - 1];
        acc += edge_term(c[ij.x], c[ij.y]);
    }

    // wave (64-lane) reduction -> one atomic per block
#pragma unroll
    for (int off = 32; off > 0; off >>= 1) acc += __shfl_down(acc, off, 64);
    __shared__ float wsum[4];
    int lane = threadIdx.x & 63;
    int wid  = threadIdx.x >> 6;
    if (lane == 0) wsum[wid] = acc;
    __syncthreads();
    if (threadIdx.x == 0) {
        float s = 0.0f;
        for (int w = 0; w < (int)(blockDim.x >> 6); ++w) s += wsum[w];
        atomicAdd(out, s * neg_inv_s);
    }
}

// ---------------- generic-S fallback (harness uses S=8; kept for safety)
__global__ void compute_c_gen(const float* __restrict__ mu, const float* __restrict__ ls,
                              const float* __restrict__ eps, __half* __restrict__ c,
                              int N, int S, float* __restrict__ out, int out_size) {
    if (blockIdx.x == gridDim.x - 1) {
        for (int i = threadIdx.x; i < out_size; i += blockDim.x) out[i] = 0.0f;
        return;
    }
    int n = blockIdx.x * blockDim.x + threadIdx.x;
    if (n >= N) return;
    float m = mu[n], sg = __expf(ls[n]);
    for (int s = 0; s < S; ++s) c[(size_t)n * S + s] = __float2half(m + sg * eps[(size_t)s * N + n]);
}
__global__ void edge_loglik_gen(const int* __restrict__ ed, const __half* __restrict__ c,
                                float* __restrict__ out, long long E, int S, float neg_inv_s) {
    long long tid = (long long)blockIdx.x * blockDim.x + threadIdx.x;
    long long stride = (long long)gridDim.x * blockDim.x;
    float acc = 0.0f;
    for (long long e = tid; e < E; e += stride) {
        long long i = ed[2 * e], j = ed[2 * e + 1];
        for (int s = 0; s < S; ++s) {
            float x = __half2float(c[i * S + s]) * __half2float(c[j * S + s]);
            acc += __logf(1.0f + fminf(__expf(-x), 1.0e8f));
        }
    }
#pragma unroll
    for (int off = 32; off > 0; off >>= 1) acc += __shfl_down(acc, off, 64);
    __shared__ float wsum[8];
    int lane = threadIdx.x & 63, wid = threadIdx.x >> 6;
    if (lane == 0) wsum[wid] = acc;
    __syncthreads();
    if (threadIdx.x == 0) {
        float s = 0.0f;
        for (int w = 0; w < (int)(blockDim.x >> 6); ++w) s += wsum[w];
        atomicAdd(out, s * neg_inv_s);
    }
}

extern "C" void kernel_launch(void* const* d_in, const int* in_sizes, int n_in,
                              void* d_out, int out_size, void* d_ws, size_t ws_size,
                              hipStream_t stream) {
    const float* mu  = (const float*)d_in[0];
    const float* ls  = (const float*)d_in[1];
    const float* eps = (const float*)d_in[2];
    const int* edges = (const int*)d_in[3];    // int32 pairs (confirmed R4/R5)

    int       N = in_sizes[0];
    int       S = in_sizes[2] / N;             // 8
    long long E = (long long)in_sizes[3] / 2;  // 3.2M

    __half* c  = (__half*)d_ws;
    float* out = (float*)d_out;
    size_t sz_c = (size_t)N * S * sizeof(__half);
    float neg_inv_s = -1.0f / (float)S;

    int cblocks = (N + 255) / 256 + 1;         // +1 block zeroes d_out

    if (S == 8 && ws_size >= sz_c) {
        compute_c_h8<<<cblocks, 256, 0, stream>>>(mu, ls, eps, (__half2*)c, N, out, out_size);
        edge_loglik_s8<<<2048, 256, 0, stream>>>((const i32x4*)edges, (const u32x4*)c,
                                                 out, E, neg_inv_s);
    } else {
        compute_c_gen<<<cblocks, 256, 0, stream>>>(mu, ls, eps, c, N, S, out, out_size);
        edge_loglik_gen<<<2048, 256, 0, stream>>>(edges, c, out, E, S, neg_inv_s);
    }
}